// Round 7
// baseline (150.671 us; speedup 1.0000x reference)
//
#include <hip/hip_runtime.h>
#include <hip/hip_fp16.h>

#define EPS 1e-8f

// ---- fused geometry: 512 blocks x 1024 thr = 2048 thr/CU (2 blocks/CU) ----
#define FBLK 1024
#define FGRID 512
#define FNP 5            // node partitions
#define FGE 96           // edge chunks: 12 per XCD * 8 XCDs (XCD-clustered)
#define FPART 20000      // bins/partition; 80 KB LDS -> exactly 2 blocks/CU

// ---- fallback (split) geometry ----
#define HBLK 1024

typedef float    v2f __attribute__((ext_vector_type(2)));
typedef float    v4f __attribute__((ext_vector_type(4)));
typedef int      v4i __attribute__((ext_vector_type(4)));
typedef unsigned v4u __attribute__((ext_vector_type(4)));

__device__ __forceinline__ float dot16_fp8(uint4 A, uint4 B) {
    const unsigned* pa = (const unsigned*)&A;
    const unsigned* pb = (const unsigned*)&B;
    float acc = 0.0f;
#pragma unroll
    for (int i = 0; i < 4; ++i) {
        v2f a01 = __builtin_amdgcn_cvt_pk_f32_fp8((int)pa[i], false);
        v2f a23 = __builtin_amdgcn_cvt_pk_f32_fp8((int)pa[i], true);
        v2f b01 = __builtin_amdgcn_cvt_pk_f32_fp8((int)pb[i], false);
        v2f b23 = __builtin_amdgcn_cvt_pk_f32_fp8((int)pb[i], true);
        acc += a01[0] * b01[0] + a01[1] * b01[1]
             + a23[0] * b23[0] + a23[1] * b23[1];
    }
    return acc;
}

__device__ __forceinline__ float sigmoidf_(float x) {
    return 1.0f / (1.0f + __expf(-x));
}

// Relaxed-poll sense-reversing barrier, split into arrive/wait so
// barrier-independent work (LDS zeroing) can overlap the skew window.
// Ordering audit: arriver's ACQ_REL fetch_add releases its phase writes;
// releaser resets cnt (relaxed) BEFORE the release-store of gen; waiters
// RELAXED-poll gen (no cache-invalidate storm; R4 lesson) then do one
// ACQUIRE load to establish ordering. wait() compares ==g, so even a
// double generation flip cannot strand a straggler.
__device__ __forceinline__ unsigned bar_arrive(unsigned* cnt, unsigned* gen,
                                               unsigned nblocks) {
    unsigned g = __hip_atomic_load(gen, __ATOMIC_RELAXED,
                                   __HIP_MEMORY_SCOPE_AGENT);
    unsigned arrived = __hip_atomic_fetch_add(cnt, 1u, __ATOMIC_ACQ_REL,
                                              __HIP_MEMORY_SCOPE_AGENT);
    if (arrived == nblocks - 1) {
        __hip_atomic_store(cnt, 0u, __ATOMIC_RELAXED,
                           __HIP_MEMORY_SCOPE_AGENT);
        __hip_atomic_store(gen, g + 1u, __ATOMIC_RELEASE,
                           __HIP_MEMORY_SCOPE_AGENT);
    }
    return g;
}

__device__ __forceinline__ void bar_wait(unsigned* gen, unsigned g) {
    while (__hip_atomic_load(gen, __ATOMIC_RELAXED,
                             __HIP_MEMORY_SCOPE_AGENT) == g) {
        __builtin_amdgcn_s_sleep(4);    // ~256 cyc backoff
    }
    while (__hip_atomic_load(gen, __ATOMIC_ACQUIRE,
                             __HIP_MEMORY_SCOPE_AGENT) == g) {}
}

__device__ __forceinline__ void grid_barrier(unsigned* cnt, unsigned* gen,
                                             unsigned nblocks) {
    __syncthreads();
    if (threadIdx.x == 0) {
        unsigned g = bar_arrive(cnt, gen, nblocks);
        bar_wait(gen, g);
    }
    __syncthreads();
}

// ---------------------------------------------------------------------------
// Fused persistent kernel v4: XCD-clustered histogram chunks + arrive/wait
// overlap of the LDS zero-init. Plain <<<>>> launch (graph-capture safe);
// co-residency proven host-side.
// ---------------------------------------------------------------------------
__global__ __launch_bounds__(FBLK, 8) void fused_kernel(
    const int* __restrict__ src, const int* __restrict__ dst,
    const float4* __restrict__ emb1, const float4* __restrict__ emb2,
    unsigned* __restrict__ q1, unsigned* __restrict__ q2,
    unsigned* __restrict__ packed, __half* __restrict__ partial,
    float* __restrict__ row_sum, float* __restrict__ out,
    unsigned* __restrict__ bar_cnt, unsigned* __restrict__ bar_gen,
    int n_edges, int n_nodes)
{
    extern __shared__ unsigned lds[];
    const int tid = threadIdx.x;
    const int bid = blockIdx.x;
    const int gt = bid * FBLK + tid;
    const int gstride = FGRID * FBLK;

    // ---- P1: fp8-convert both emb tables ----
    int n4 = n_nodes * 4;                 // EMB_DIM=16 -> 4 float4 per row
    for (int i = gt; i < n4; i += gstride) {
        float4 a = emb1[i];
        float4 b = emb2[i];
        int pa = __builtin_amdgcn_cvt_pk_fp8_f32(a.x, a.y, 0, false);
        pa     = __builtin_amdgcn_cvt_pk_fp8_f32(a.z, a.w, pa, true);
        int pb = __builtin_amdgcn_cvt_pk_fp8_f32(b.x, b.y, 0, false);
        pb     = __builtin_amdgcn_cvt_pk_fp8_f32(b.z, b.w, pb, true);
        q1[i] = (unsigned)pa;
        q2[i] = (unsigned)pb;
    }
    grid_barrier(bar_cnt, bar_gen, FGRID);

    // ---- P2: gather + dot + sigmoid -> packed (src<<15 | w15) ----
    const uint4* q1r = (const uint4*)q1;
    const uint4* q2r = (const uint4*)q2;
    int nq = n_edges >> 2;
    for (int t = gt; t < nq; t += gstride) {
        v4i s = __builtin_nontemporal_load((const v4i*)src + t);
        v4i d = __builtin_nontemporal_load((const v4i*)dst + t);
        uint4 A0 = q1r[s.x];
        uint4 A1 = q1r[s.y];
        uint4 A2 = q1r[s.z];
        uint4 A3 = q1r[s.w];
        uint4 B0 = q2r[d.x];
        uint4 B1 = q2r[d.y];
        uint4 B2 = q2r[d.z];
        uint4 B3 = q2r[d.w];
        float w0 = sigmoidf_(dot16_fp8(A0, B0));
        float w1 = sigmoidf_(dot16_fp8(A1, B1));
        float w2 = sigmoidf_(dot16_fp8(A2, B2));
        float w3 = sigmoidf_(dot16_fp8(A3, B3));
        v4u pk;
        pk.x = ((unsigned)s.x << 15) | __float2uint_rn(w0 * 32767.0f);
        pk.y = ((unsigned)s.y << 15) | __float2uint_rn(w1 * 32767.0f);
        pk.z = ((unsigned)s.z << 15) | __float2uint_rn(w2 * 32767.0f);
        pk.w = ((unsigned)s.w << 15) | __float2uint_rn(w3 * 32767.0f);
        ((v4u*)packed)[t] = pk;
    }
    if (gt == 0) {                         // scalar tail (n_edges % 4)
        for (int e = nq << 2; e < n_edges; ++e) {
            int ss = src[e];
            float wv = sigmoidf_(dot16_fp8(q1r[ss], q2r[dst[e]]));
            packed[e] = ((unsigned)ss << 15) | __float2uint_rn(wv * 32767.0f);
        }
    }

    // ---- barrier 2 with arrive/wait split: zero the histogram while the
    //      grid drains (LDS is barrier-independent) ----
    // XCD-clustered chunk mapping: the FNP blocks sharing chunk c all live
    // on one XCD -> chunk fetched from L3 once, re-read from local L2.
    // (bid->XCD assumed round-robin bid%8; if mapping differs this only
    //  costs locality, never correctness.)
    int xcd = bid & 7;
    int slt = bid >> 3;                    // 0..63 within XCD
    bool hactive = (slt < FNP * 12);       // 12 chunks/XCD * 5 partitions
    int c = xcd * 12 + slt / FNP;          // 0..95
    int p = slt % FNP;
    int base = p * FPART;

    __syncthreads();
    unsigned g2 = 0;
    if (tid == 0) g2 = bar_arrive(bar_cnt, bar_gen, FGRID);
    if (hactive)
        for (int i = tid; i < FPART; i += FBLK) lds[i] = 0u;
    if (tid == 0) bar_wait(bar_gen, g2);
    __syncthreads();

    // ---- P3: LDS-privatized histogram (u32 fixed point; per-chunk max
    //      ~33.4K edges * 32767 = 1.1e9 < 2^32, no overflow) ----
    if (hactive) {
        int per = (nq + FGE - 1) / FGE;
        int q0 = c * per;
        int q1e = min(q0 + per, nq);
        const v4u* p4 = (const v4u*)packed;
        for (int q = q0 + tid; q < q1e; q += FBLK) {
            v4u pk = p4[q];
            unsigned i0 = (pk.x >> 15) - base;
            unsigned i1 = (pk.y >> 15) - base;
            unsigned i2 = (pk.z >> 15) - base;
            unsigned i3 = (pk.w >> 15) - base;
            if (i0 < (unsigned)FPART) atomicAdd(&lds[i0], pk.x & 32767u);
            if (i1 < (unsigned)FPART) atomicAdd(&lds[i1], pk.y & 32767u);
            if (i2 < (unsigned)FPART) atomicAdd(&lds[i2], pk.z & 32767u);
            if (i3 < (unsigned)FPART) atomicAdd(&lds[i3], pk.w & 32767u);
        }
        if (c == FGE - 1) {                // scalar tail
            for (int e = (nq << 2) + tid; e < n_edges; e += FBLK) {
                unsigned pk = packed[e];
                unsigned i = (pk >> 15) - base;
                if (i < (unsigned)FPART) atomicAdd(&lds[i], pk & 32767u);
            }
        }
        __syncthreads();

        const float inv = 1.0f / 32767.0f;
        int lim = min(FPART, n_nodes - base);
        size_t pb = (size_t)c * n_nodes + base;
        for (int i = tid; i < lim; i += FBLK)
            partial[pb + i] = __float2half((float)lds[i] * inv);
    }
    grid_barrier(bar_cnt, bar_gen, FGRID);

    // ---- P4: fold partials -> row_sum ----
    for (int n = gt; n < n_nodes; n += gstride) {
        float acc = 0.0f;
        for (int cc = 0; cc < FGE; ++cc)
            acc += __half2float(partial[(size_t)cc * n_nodes + n]);
        row_sum[n] = acc;
    }
    grid_barrier(bar_cnt, bar_gen, FGRID);

    // ---- P5: normalize (8 edges/thread); packed's last use -> nt loads;
    //      out is write-once stream -> nt stores ----
    const float inv = 1.0f / 32767.0f;
    int n_oct = n_edges >> 3;
    for (int t = gt; t < n_oct; t += gstride) {
        v4u pa = __builtin_nontemporal_load((const v4u*)packed + t * 2);
        v4u pb = __builtin_nontemporal_load((const v4u*)packed + t * 2 + 1);
        float r0 = row_sum[pa.x >> 15];
        float r1 = row_sum[pa.y >> 15];
        float r2 = row_sum[pa.z >> 15];
        float r3 = row_sum[pa.w >> 15];
        float r4 = row_sum[pb.x >> 15];
        float r5 = row_sum[pb.y >> 15];
        float r6 = row_sum[pb.z >> 15];
        float r7 = row_sum[pb.w >> 15];
        v4f oa, ob;
        oa.x = (float)(pa.x & 32767u) * inv / (r0 + EPS);
        oa.y = (float)(pa.y & 32767u) * inv / (r1 + EPS);
        oa.z = (float)(pa.z & 32767u) * inv / (r2 + EPS);
        oa.w = (float)(pa.w & 32767u) * inv / (r3 + EPS);
        ob.x = (float)(pb.x & 32767u) * inv / (r4 + EPS);
        ob.y = (float)(pb.y & 32767u) * inv / (r5 + EPS);
        ob.z = (float)(pb.z & 32767u) * inv / (r6 + EPS);
        ob.w = (float)(pb.w & 32767u) * inv / (r7 + EPS);
        __builtin_nontemporal_store(oa, (v4f*)out + t * 2);
        __builtin_nontemporal_store(ob, (v4f*)out + t * 2 + 1);
    }
    if (gt == 0) {                         // tail (n_edges % 8)
        for (int e = n_oct << 3; e < n_edges; ++e) {
            unsigned pk = packed[e];
            out[e] = (float)(pk & 32767u) * inv / (row_sum[pk >> 15] + EPS);
        }
    }
}

// ---------------------------------------------------------------------------
// Fallback split kernels (verified pipeline).
// ---------------------------------------------------------------------------
__global__ __launch_bounds__(256) void convert_fp8_kernel(
    const float4* __restrict__ emb1, const float4* __restrict__ emb2,
    unsigned* __restrict__ q1, unsigned* __restrict__ q2, int n4)
{
    int i = blockIdx.x * blockDim.x + threadIdx.x;
    if (i >= n4) return;
    float4 a = emb1[i];
    float4 b = emb2[i];
    int pa = __builtin_amdgcn_cvt_pk_fp8_f32(a.x, a.y, 0, false);
    pa     = __builtin_amdgcn_cvt_pk_fp8_f32(a.z, a.w, pa, true);
    int pb = __builtin_amdgcn_cvt_pk_fp8_f32(b.x, b.y, 0, false);
    pb     = __builtin_amdgcn_cvt_pk_fp8_f32(b.z, b.w, pb, true);
    q1[i] = (unsigned)pa;
    q2[i] = (unsigned)pb;
}

__global__ __launch_bounds__(256) void gather_pack_kernel(
    const int* __restrict__ src, const int* __restrict__ dst,
    const uint4* __restrict__ q1, const uint4* __restrict__ q2,
    unsigned* __restrict__ packed, int n_edges)
{
    int t = blockIdx.x * blockDim.x + threadIdx.x;
    int nq = n_edges >> 2;
    if (t < nq) {
        v4i s = __builtin_nontemporal_load((const v4i*)src + t);
        v4i d = __builtin_nontemporal_load((const v4i*)dst + t);
        uint4 A0 = q1[s.x];
        uint4 A1 = q1[s.y];
        uint4 A2 = q1[s.z];
        uint4 A3 = q1[s.w];
        uint4 B0 = q2[d.x];
        uint4 B1 = q2[d.y];
        uint4 B2 = q2[d.z];
        uint4 B3 = q2[d.w];
        float w0 = sigmoidf_(dot16_fp8(A0, B0));
        float w1 = sigmoidf_(dot16_fp8(A1, B1));
        float w2 = sigmoidf_(dot16_fp8(A2, B2));
        float w3 = sigmoidf_(dot16_fp8(A3, B3));
        v4u pk;
        pk.x = ((unsigned)s.x << 15) | __float2uint_rn(w0 * 32767.0f);
        pk.y = ((unsigned)s.y << 15) | __float2uint_rn(w1 * 32767.0f);
        pk.z = ((unsigned)s.z << 15) | __float2uint_rn(w2 * 32767.0f);
        pk.w = ((unsigned)s.w << 15) | __float2uint_rn(w3 * 32767.0f);
        ((v4u*)packed)[t] = pk;
    }
    if (t == 0) {
        for (int e = nq << 2; e < n_edges; ++e) {
            int ss = src[e];
            float wv = sigmoidf_(dot16_fp8(q1[ss], q2[dst[e]]));
            packed[e] = ((unsigned)ss << 15) | __float2uint_rn(wv * 32767.0f);
        }
    }
}

__global__ __launch_bounds__(HBLK) void hist_kernel(
    const unsigned* __restrict__ packed, __half* __restrict__ partial,
    int n_edges, int n_nodes, int PARTr, int NPr, int GEr)
{
    extern __shared__ unsigned ldsf[];
    int bid = blockIdx.x;
    int c = bid / NPr;
    int p = bid % NPr;
    int tid = threadIdx.x;
    int base = p * PARTr;

    for (int i = tid; i < PARTr; i += HBLK) ldsf[i] = 0u;
    __syncthreads();

    int nq = n_edges >> 2;
    int per = (nq + GEr - 1) / GEr;
    int q0 = c * per;
    int q1e = min(q0 + per, nq);

    const v4u* p4 = (const v4u*)packed;
    for (int q = q0 + tid; q < q1e; q += HBLK) {
        v4u pk = p4[q];
        unsigned i0 = (pk.x >> 15) - base;
        unsigned i1 = (pk.y >> 15) - base;
        unsigned i2 = (pk.z >> 15) - base;
        unsigned i3 = (pk.w >> 15) - base;
        if (i0 < (unsigned)PARTr) atomicAdd(&ldsf[i0], pk.x & 32767u);
        if (i1 < (unsigned)PARTr) atomicAdd(&ldsf[i1], pk.y & 32767u);
        if (i2 < (unsigned)PARTr) atomicAdd(&ldsf[i2], pk.z & 32767u);
        if (i3 < (unsigned)PARTr) atomicAdd(&ldsf[i3], pk.w & 32767u);
    }
    if (c == GEr - 1) {
        for (int e = (nq << 2) + tid; e < n_edges; e += HBLK) {
            unsigned pk = packed[e];
            unsigned i = (pk >> 15) - base;
            if (i < (unsigned)PARTr) atomicAdd(&ldsf[i], pk & 32767u);
        }
    }
    __syncthreads();

    const float inv = 1.0f / 32767.0f;
    int lim = min(PARTr, n_nodes - base);
    size_t pb = (size_t)c * n_nodes + base;
    for (int i = tid; i < lim; i += HBLK)
        partial[pb + i] = __float2half((float)ldsf[i] * inv);
}

__global__ __launch_bounds__(256) void fold_kernel(
    const __half* __restrict__ partial, float* __restrict__ row_sum,
    int n_nodes, int GEr)
{
    int n = blockIdx.x * blockDim.x + threadIdx.x;
    if (n >= n_nodes) return;
    float acc = 0.0f;
#pragma unroll 4
    for (int c = 0; c < GEr; ++c)
        acc += __half2float(partial[(size_t)c * n_nodes + n]);
    row_sum[n] = acc;
}

__global__ __launch_bounds__(256) void edge_norm_kernel(
    const unsigned* __restrict__ packed, const float* __restrict__ row_sum,
    float* __restrict__ out, int n_edges)
{
    int t = blockIdx.x * blockDim.x + threadIdx.x;
    int e0 = t * 8;
    const float inv = 1.0f / 32767.0f;
    if (e0 + 7 < n_edges) {
        v4u pa = ((const v4u*)packed)[t * 2];
        v4u pb = ((const v4u*)packed)[t * 2 + 1];
        float r0 = row_sum[pa.x >> 15];
        float r1 = row_sum[pa.y >> 15];
        float r2 = row_sum[pa.z >> 15];
        float r3 = row_sum[pa.w >> 15];
        float r4 = row_sum[pb.x >> 15];
        float r5 = row_sum[pb.y >> 15];
        float r6 = row_sum[pb.z >> 15];
        float r7 = row_sum[pb.w >> 15];
        v4f oa, ob;
        oa.x = (float)(pa.x & 32767u) * inv / (r0 + EPS);
        oa.y = (float)(pa.y & 32767u) * inv / (r1 + EPS);
        oa.z = (float)(pa.z & 32767u) * inv / (r2 + EPS);
        oa.w = (float)(pa.w & 32767u) * inv / (r3 + EPS);
        ob.x = (float)(pb.x & 32767u) * inv / (r4 + EPS);
        ob.y = (float)(pb.y & 32767u) * inv / (r5 + EPS);
        ob.z = (float)(pb.z & 32767u) * inv / (r6 + EPS);
        ob.w = (float)(pb.w & 32767u) * inv / (r7 + EPS);
        __builtin_nontemporal_store(oa, (v4f*)out + t * 2);
        __builtin_nontemporal_store(ob, (v4f*)out + t * 2 + 1);
    } else if (e0 < n_edges) {
        for (int e = e0; e < n_edges; ++e) {
            unsigned pk = packed[e];
            out[e] = (float)(pk & 32767u) * inv / (row_sum[pk >> 15] + EPS);
        }
    }
}

extern "C" void kernel_launch(void* const* d_in, const int* in_sizes, int n_in,
                              void* d_out, int out_size, void* d_ws, size_t ws_size,
                              hipStream_t stream) {
    const int*    src  = (const int*)d_in[0];
    const int*    dst  = (const int*)d_in[1];
    const float4* emb1 = (const float4*)d_in[2];
    const float4* emb2 = (const float4*)d_in[3];
    float* out = (float*)d_out;

    int n_edges = in_sizes[0];
    int n_emb   = in_sizes[2];          // N_NODES * 16 floats
    int n_nodes = n_emb / 16;

    // ws layout (16B-aligned):
    //   bar     : 128 B (grid-barrier cnt/gen)
    //   row_sum : n_nodes f32            (400 KB)
    //   packed  : n_edges u32            (12.8 MB)
    //   q1, q2  : n_emb fp8              (1.6 MB each)
    //   partial : FGE*n_nodes f16        (19.2 MB)
    char* base = (char*)d_ws;
    unsigned* bar = (unsigned*)base;
    size_t off = 128;
    float* row_sum = (float*)(base + off);
    off += ((size_t)n_nodes * sizeof(float) + 15) & ~(size_t)15;
    unsigned* packed = (unsigned*)(base + off);
    off += ((size_t)n_edges * sizeof(unsigned) + 15) & ~(size_t)15;
    unsigned* q1 = (unsigned*)(base + off);
    off += ((size_t)n_emb + 15) & ~(size_t)15;
    unsigned* q2 = (unsigned*)(base + off);
    off += ((size_t)n_emb + 15) & ~(size_t)15;
    __half* partial = (__half*)(base + off);

    // One-time host-side checks: dynamic-LDS cap + EXACT co-residency proof.
    static int fused_ok = -1;
    if (fused_ok < 0) {
        int dev = 0;
        hipGetDevice(&dev);
        hipError_t e = hipFuncSetAttribute(
            reinterpret_cast<const void*>(&fused_kernel),
            hipFuncAttributeMaxDynamicSharedMemorySize, FPART * 4);
        int nb = 0;
        if (e == hipSuccess)
            e = hipOccupancyMaxActiveBlocksPerMultiprocessor(
                &nb, reinterpret_cast<const void*>(&fused_kernel),
                FBLK, (size_t)FPART * 4);
        int ncu = 0;
        hipDeviceGetAttribute(&ncu, hipDeviceAttributeMultiprocessorCount, dev);
        fused_ok = (e == hipSuccess && nb >= 1 &&
                    (long)nb * ncu >= FGRID) ? 1 : 0;
    }

    if (fused_ok && n_nodes <= FNP * FPART) {
        hipMemsetAsync(bar, 0, 8, stream);   // ws is poisoned between runs
        fused_kernel<<<FGRID, FBLK, (size_t)FPART * 4, stream>>>(
            src, dst, emb1, emb2, q1, q2, packed, partial,
            row_sum, out, bar, bar + 1, n_edges, n_nodes);
        return;
    }

    // ---- fallback: verified split pipeline ----
    static int use_big = -1;
    if (use_big < 0) {
        hipError_t e = hipFuncSetAttribute(
            reinterpret_cast<const void*>(&hist_kernel),
            hipFuncAttributeMaxDynamicSharedMemorySize, 25000 * 4);
        use_big = (e == hipSuccess) ? 1 : 0;
    }
    int PARTr = use_big ? 25000 : 16000;
    int NPr   = use_big ? 4     : 7;
    int GEr   = use_big ? 64    : 37;
    size_t lds_bytes = (size_t)PARTr * sizeof(unsigned);

    int block = 256;
    int n4 = n_emb / 4;
    convert_fp8_kernel<<<(n4 + block - 1) / block, block, 0, stream>>>(
        emb1, emb2, q1, q2, n4);

    int nq = n_edges >> 2;
    int gblocks = (nq + block - 1) / block;
    if (gblocks < 1) gblocks = 1;
    gather_pack_kernel<<<gblocks, block, 0, stream>>>(
        src, dst, (const uint4*)q1, (const uint4*)q2, packed, n_edges);

    hist_kernel<<<GEr * NPr, HBLK, lds_bytes, stream>>>(
        packed, partial, n_edges, n_nodes, PARTr, NPr, GEr);

    fold_kernel<<<(n_nodes + block - 1) / block, block, 0, stream>>>(
        partial, row_sum, n_nodes, GEr);

    int n_oct = (n_edges + 7) / 8;
    edge_norm_kernel<<<(n_oct + block - 1) / block, block, 0, stream>>>(
        packed, row_sum, out, n_edges);
}

// Round 8
// 150.121 us; speedup vs baseline: 1.0037x; 1.0037x over previous
//
#include <hip/hip_runtime.h>
#include <hip/hip_fp16.h>

#define EPS 1e-8f

// ---- fused geometry: 480 blocks = 96 chunks x 5 partitions, 1024 thr ----
#define FBLK 1024
#define FGRID 480
#define FNP 5            // node partitions
#define FGE 96           // edge chunks: 12 per XCD * 8 XCDs
#define FPART 20000      // bins/partition; 80 KB LDS -> 2 blocks/CU

// ---- fallback (split) geometry ----
#define HBLK 1024

typedef float    v2f __attribute__((ext_vector_type(2)));
typedef float    v4f __attribute__((ext_vector_type(4)));
typedef int      v4i __attribute__((ext_vector_type(4)));
typedef unsigned v4u __attribute__((ext_vector_type(4)));

__device__ __forceinline__ float dot16_fp8(uint4 A, uint4 B) {
    const unsigned* pa = (const unsigned*)&A;
    const unsigned* pb = (const unsigned*)&B;
    float acc = 0.0f;
#pragma unroll
    for (int i = 0; i < 4; ++i) {
        v2f a01 = __builtin_amdgcn_cvt_pk_f32_fp8((int)pa[i], false);
        v2f a23 = __builtin_amdgcn_cvt_pk_f32_fp8((int)pa[i], true);
        v2f b01 = __builtin_amdgcn_cvt_pk_f32_fp8((int)pb[i], false);
        v2f b23 = __builtin_amdgcn_cvt_pk_f32_fp8((int)pb[i], true);
        acc += a01[0] * b01[0] + a01[1] * b01[1]
             + a23[0] * b23[0] + a23[1] * b23[1];
    }
    return acc;
}

__device__ __forceinline__ float sigmoidf_(float x) {
    return 1.0f / (1.0f + __expf(-x));
}

// Relaxed-poll sense-reversing global barrier (R5/R6-validated: RELAXED spin
// avoids the acquire cache-invalidate storm; one ACQUIRE load after the flip
// establishes ordering; arriver's ACQ_REL fetch_add releases phase writes).
__device__ __forceinline__ unsigned bar_arrive(unsigned* cnt, unsigned* gen,
                                               unsigned nblocks) {
    unsigned g = __hip_atomic_load(gen, __ATOMIC_RELAXED,
                                   __HIP_MEMORY_SCOPE_AGENT);
    unsigned arrived = __hip_atomic_fetch_add(cnt, 1u, __ATOMIC_ACQ_REL,
                                              __HIP_MEMORY_SCOPE_AGENT);
    if (arrived == nblocks - 1) {
        __hip_atomic_store(cnt, 0u, __ATOMIC_RELAXED,
                           __HIP_MEMORY_SCOPE_AGENT);
        __hip_atomic_store(gen, g + 1u, __ATOMIC_RELEASE,
                           __HIP_MEMORY_SCOPE_AGENT);
    }
    return g;
}

__device__ __forceinline__ void bar_wait(unsigned* gen, unsigned g) {
    while (__hip_atomic_load(gen, __ATOMIC_RELAXED,
                             __HIP_MEMORY_SCOPE_AGENT) == g) {
        __builtin_amdgcn_s_sleep(4);
    }
    while (__hip_atomic_load(gen, __ATOMIC_ACQUIRE,
                             __HIP_MEMORY_SCOPE_AGENT) == g) {}
}

__device__ __forceinline__ void grid_barrier(unsigned* cnt, unsigned* gen,
                                             unsigned nblocks) {
    __syncthreads();
    if (threadIdx.x == 0) {
        unsigned g = bar_arrive(cnt, gen, nblocks);
        bar_wait(gen, g);
    }
    __syncthreads();
}

// ---------------------------------------------------------------------------
// Fused persistent kernel v5: per-chunk producer/consumer sync replaces the
// P2->P3 global barrier. The 5 blocks of chunk-group c produce chunk c's
// packed slice (1/5 each), mini-sync on chunk_bar[c], then histogram their
// own chunk (same-XCD L2-hot). 3 global barriers remain (A: q tables,
// B: partial, C: row_sum).
// ---------------------------------------------------------------------------
__global__ __launch_bounds__(FBLK, 8) void fused_kernel(
    const int* __restrict__ src, const int* __restrict__ dst,
    const float4* __restrict__ emb1, const float4* __restrict__ emb2,
    unsigned* __restrict__ q1, unsigned* __restrict__ q2,
    unsigned* __restrict__ packed, __half* __restrict__ partial,
    float* __restrict__ row_sum, float* __restrict__ out,
    unsigned* __restrict__ bar, int n_edges, int n_nodes)
{
    extern __shared__ unsigned lds[];
    const int tid = threadIdx.x;
    const int bid = blockIdx.x;
    const int gt = bid * FBLK + tid;
    const int gstride = FGRID * FBLK;
    unsigned* bar_cnt  = bar;           // global barrier counter
    unsigned* bar_gen  = bar + 1;       // global barrier generation
    unsigned* chunk_bar = bar + 2;      // 96 per-chunk arrival counters

    // Chunk-group mapping, XCD-clustered (bid%8 = XCD assumed round-robin;
    // wrong mapping costs locality only, never correctness):
    //   x = bid&7 (XCD), t = bid>>3, chunk c = 8*(t/5)+x, partition j = t%5
    const int x = bid & 7;
    const int t_ = bid >> 3;
    const int c = 8 * (t_ / FNP) + x;      // 0..95
    const int j = t_ % FNP;                // 0..4
    const int base = j * FPART;

    // ---- P1: fp8-convert both emb tables ----
    int n4 = n_nodes * 4;                  // EMB_DIM=16 -> 4 float4 per row
    for (int i = gt; i < n4; i += gstride) {
        float4 a = emb1[i];
        float4 b = emb2[i];
        int pa = __builtin_amdgcn_cvt_pk_fp8_f32(a.x, a.y, 0, false);
        pa     = __builtin_amdgcn_cvt_pk_fp8_f32(a.z, a.w, pa, true);
        int pb = __builtin_amdgcn_cvt_pk_fp8_f32(b.x, b.y, 0, false);
        pb     = __builtin_amdgcn_cvt_pk_fp8_f32(b.z, b.w, pb, true);
        q1[i] = (unsigned)pa;
        q2[i] = (unsigned)pb;
    }
    grid_barrier(bar_cnt, bar_gen, FGRID);     // A: q tables ready

    // ---- P2: produce THIS group's chunk slice (1/5 of chunk c) ----
    const uint4* q1r = (const uint4*)q1;
    const uint4* q2r = (const uint4*)q2;
    int nq  = n_edges >> 2;
    int per = (nq + FGE - 1) / FGE;
    int q0c = c * per;
    int q1c = min(q0c + per, nq);
    int sper = (per + FNP - 1) / FNP;
    int qa = q0c + j * sper;
    int qb = min(qa + sper, q1c);
    for (int t = qa + tid; t < qb; t += FBLK) {
        v4i s = __builtin_nontemporal_load((const v4i*)src + t);
        v4i d = __builtin_nontemporal_load((const v4i*)dst + t);
        uint4 A0 = q1r[s.x];
        uint4 A1 = q1r[s.y];
        uint4 A2 = q1r[s.z];
        uint4 A3 = q1r[s.w];
        uint4 B0 = q2r[d.x];
        uint4 B1 = q2r[d.y];
        uint4 B2 = q2r[d.z];
        uint4 B3 = q2r[d.w];
        float w0 = sigmoidf_(dot16_fp8(A0, B0));
        float w1 = sigmoidf_(dot16_fp8(A1, B1));
        float w2 = sigmoidf_(dot16_fp8(A2, B2));
        float w3 = sigmoidf_(dot16_fp8(A3, B3));
        v4u pk;
        pk.x = ((unsigned)s.x << 15) | __float2uint_rn(w0 * 32767.0f);
        pk.y = ((unsigned)s.y << 15) | __float2uint_rn(w1 * 32767.0f);
        pk.z = ((unsigned)s.z << 15) | __float2uint_rn(w2 * 32767.0f);
        pk.w = ((unsigned)s.w << 15) | __float2uint_rn(w3 * 32767.0f);
        ((v4u*)packed)[t] = pk;            // normal store: L2-hot for P3
    }
    if (c == FGE - 1 && j == FNP - 1 && tid == 0) {   // scalar tail
        for (int e = nq << 2; e < n_edges; ++e) {
            int ss = src[e];
            float wv = sigmoidf_(dot16_fp8(q1r[ss], q2r[dst[e]]));
            packed[e] = ((unsigned)ss << 15) | __float2uint_rn(wv * 32767.0f);
        }
    }

    // ---- mini-barrier on chunk c (5 arrivals); zero LDS in the window ----
    __syncthreads();                       // slice stores complete
    if (tid == 0)
        __hip_atomic_fetch_add(&chunk_bar[c], 1u, __ATOMIC_ACQ_REL,
                               __HIP_MEMORY_SCOPE_AGENT);
    for (int i = tid; i < FPART; i += FBLK) lds[i] = 0u;
    if (tid == 0) {
        while (__hip_atomic_load(&chunk_bar[c], __ATOMIC_RELAXED,
                                 __HIP_MEMORY_SCOPE_AGENT) < (unsigned)FNP) {
            __builtin_amdgcn_s_sleep(2);
        }
        (void)__hip_atomic_load(&chunk_bar[c], __ATOMIC_ACQUIRE,
                                __HIP_MEMORY_SCOPE_AGENT);
    }
    __syncthreads();

    // ---- P3: LDS hist of full chunk c, partition j (u32 fixed point;
    //      per-chunk max ~33.4K edges * 32767 = 1.09e9 < 2^32) ----
    {
        const v4u* p4 = (const v4u*)packed;
        for (int q = q0c + tid; q < q1c; q += FBLK) {
            v4u pk = p4[q];
            unsigned i0 = (pk.x >> 15) - base;
            unsigned i1 = (pk.y >> 15) - base;
            unsigned i2 = (pk.z >> 15) - base;
            unsigned i3 = (pk.w >> 15) - base;
            if (i0 < (unsigned)FPART) atomicAdd(&lds[i0], pk.x & 32767u);
            if (i1 < (unsigned)FPART) atomicAdd(&lds[i1], pk.y & 32767u);
            if (i2 < (unsigned)FPART) atomicAdd(&lds[i2], pk.z & 32767u);
            if (i3 < (unsigned)FPART) atomicAdd(&lds[i3], pk.w & 32767u);
        }
        if (c == FGE - 1) {                // scalar tail edges
            for (int e = (nq << 2) + tid; e < n_edges; e += FBLK) {
                unsigned pk = packed[e];
                unsigned i = (pk >> 15) - base;
                if (i < (unsigned)FPART) atomicAdd(&lds[i], pk & 32767u);
            }
        }
        __syncthreads();

        const float inv = 1.0f / 32767.0f;
        int lim = min(FPART, n_nodes - base);
        size_t pb = (size_t)c * n_nodes + base;
        for (int i = tid; i < lim; i += FBLK)
            partial[pb + i] = __float2half((float)lds[i] * inv);
    }
    grid_barrier(bar_cnt, bar_gen, FGRID);     // B: all partials ready

    // ---- P4: fold partials -> row_sum ----
    for (int n = gt; n < n_nodes; n += gstride) {
        float acc = 0.0f;
        for (int cc = 0; cc < FGE; ++cc)
            acc += __half2float(partial[(size_t)cc * n_nodes + n]);
        row_sum[n] = acc;
    }
    grid_barrier(bar_cnt, bar_gen, FGRID);     // C: row_sum ready

    // ---- P5: normalize (8 edges/thread); nt loads/stores ----
    const float inv = 1.0f / 32767.0f;
    int n_oct = n_edges >> 3;
    for (int t = gt; t < n_oct; t += gstride) {
        v4u pa = __builtin_nontemporal_load((const v4u*)packed + t * 2);
        v4u pb = __builtin_nontemporal_load((const v4u*)packed + t * 2 + 1);
        float r0 = row_sum[pa.x >> 15];
        float r1 = row_sum[pa.y >> 15];
        float r2 = row_sum[pa.z >> 15];
        float r3 = row_sum[pa.w >> 15];
        float r4 = row_sum[pb.x >> 15];
        float r5 = row_sum[pb.y >> 15];
        float r6 = row_sum[pb.z >> 15];
        float r7 = row_sum[pb.w >> 15];
        v4f oa, ob;
        oa.x = (float)(pa.x & 32767u) * inv / (r0 + EPS);
        oa.y = (float)(pa.y & 32767u) * inv / (r1 + EPS);
        oa.z = (float)(pa.z & 32767u) * inv / (r2 + EPS);
        oa.w = (float)(pa.w & 32767u) * inv / (r3 + EPS);
        ob.x = (float)(pb.x & 32767u) * inv / (r4 + EPS);
        ob.y = (float)(pb.y & 32767u) * inv / (r5 + EPS);
        ob.z = (float)(pb.z & 32767u) * inv / (r6 + EPS);
        ob.w = (float)(pb.w & 32767u) * inv / (r7 + EPS);
        __builtin_nontemporal_store(oa, (v4f*)out + t * 2);
        __builtin_nontemporal_store(ob, (v4f*)out + t * 2 + 1);
    }
    if (gt == 0) {                         // tail (n_edges % 8)
        for (int e = n_oct << 3; e < n_edges; ++e) {
            unsigned pk = packed[e];
            out[e] = (float)(pk & 32767u) * inv / (row_sum[pk >> 15] + EPS);
        }
    }
}

// ---------------------------------------------------------------------------
// Fallback split kernels (verified pipeline).
// ---------------------------------------------------------------------------
__global__ __launch_bounds__(256) void convert_fp8_kernel(
    const float4* __restrict__ emb1, const float4* __restrict__ emb2,
    unsigned* __restrict__ q1, unsigned* __restrict__ q2, int n4)
{
    int i = blockIdx.x * blockDim.x + threadIdx.x;
    if (i >= n4) return;
    float4 a = emb1[i];
    float4 b = emb2[i];
    int pa = __builtin_amdgcn_cvt_pk_fp8_f32(a.x, a.y, 0, false);
    pa     = __builtin_amdgcn_cvt_pk_fp8_f32(a.z, a.w, pa, true);
    int pb = __builtin_amdgcn_cvt_pk_fp8_f32(b.x, b.y, 0, false);
    pb     = __builtin_amdgcn_cvt_pk_fp8_f32(b.z, b.w, pb, true);
    q1[i] = (unsigned)pa;
    q2[i] = (unsigned)pb;
}

__global__ __launch_bounds__(256) void gather_pack_kernel(
    const int* __restrict__ src, const int* __restrict__ dst,
    const uint4* __restrict__ q1, const uint4* __restrict__ q2,
    unsigned* __restrict__ packed, int n_edges)
{
    int t = blockIdx.x * blockDim.x + threadIdx.x;
    int nq = n_edges >> 2;
    if (t < nq) {
        v4i s = __builtin_nontemporal_load((const v4i*)src + t);
        v4i d = __builtin_nontemporal_load((const v4i*)dst + t);
        uint4 A0 = q1[s.x];
        uint4 A1 = q1[s.y];
        uint4 A2 = q1[s.z];
        uint4 A3 = q1[s.w];
        uint4 B0 = q2[d.x];
        uint4 B1 = q2[d.y];
        uint4 B2 = q2[d.z];
        uint4 B3 = q2[d.w];
        float w0 = sigmoidf_(dot16_fp8(A0, B0));
        float w1 = sigmoidf_(dot16_fp8(A1, B1));
        float w2 = sigmoidf_(dot16_fp8(A2, B2));
        float w3 = sigmoidf_(dot16_fp8(A3, B3));
        v4u pk;
        pk.x = ((unsigned)s.x << 15) | __float2uint_rn(w0 * 32767.0f);
        pk.y = ((unsigned)s.y << 15) | __float2uint_rn(w1 * 32767.0f);
        pk.z = ((unsigned)s.z << 15) | __float2uint_rn(w2 * 32767.0f);
        pk.w = ((unsigned)s.w << 15) | __float2uint_rn(w3 * 32767.0f);
        ((v4u*)packed)[t] = pk;
    }
    if (t == 0) {
        for (int e = nq << 2; e < n_edges; ++e) {
            int ss = src[e];
            float wv = sigmoidf_(dot16_fp8(q1[ss], q2[dst[e]]));
            packed[e] = ((unsigned)ss << 15) | __float2uint_rn(wv * 32767.0f);
        }
    }
}

__global__ __launch_bounds__(HBLK) void hist_kernel(
    const unsigned* __restrict__ packed, __half* __restrict__ partial,
    int n_edges, int n_nodes, int PARTr, int NPr, int GEr)
{
    extern __shared__ unsigned ldsf[];
    int bid = blockIdx.x;
    int c = bid / NPr;
    int p = bid % NPr;
    int tid = threadIdx.x;
    int base = p * PARTr;

    for (int i = tid; i < PARTr; i += HBLK) ldsf[i] = 0u;
    __syncthreads();

    int nq = n_edges >> 2;
    int per = (nq + GEr - 1) / GEr;
    int q0 = c * per;
    int q1e = min(q0 + per, nq);

    const v4u* p4 = (const v4u*)packed;
    for (int q = q0 + tid; q < q1e; q += HBLK) {
        v4u pk = p4[q];
        unsigned i0 = (pk.x >> 15) - base;
        unsigned i1 = (pk.y >> 15) - base;
        unsigned i2 = (pk.z >> 15) - base;
        unsigned i3 = (pk.w >> 15) - base;
        if (i0 < (unsigned)PARTr) atomicAdd(&ldsf[i0], pk.x & 32767u);
        if (i1 < (unsigned)PARTr) atomicAdd(&ldsf[i1], pk.y & 32767u);
        if (i2 < (unsigned)PARTr) atomicAdd(&ldsf[i2], pk.z & 32767u);
        if (i3 < (unsigned)PARTr) atomicAdd(&ldsf[i3], pk.w & 32767u);
    }
    if (c == GEr - 1) {
        for (int e = (nq << 2) + tid; e < n_edges; e += HBLK) {
            unsigned pk = packed[e];
            unsigned i = (pk >> 15) - base;
            if (i < (unsigned)PARTr) atomicAdd(&ldsf[i], pk & 32767u);
        }
    }
    __syncthreads();

    const float inv = 1.0f / 32767.0f;
    int lim = min(PARTr, n_nodes - base);
    size_t pb = (size_t)c * n_nodes + base;
    for (int i = tid; i < lim; i += HBLK)
        partial[pb + i] = __float2half((float)ldsf[i] * inv);
}

__global__ __launch_bounds__(256) void fold_kernel(
    const __half* __restrict__ partial, float* __restrict__ row_sum,
    int n_nodes, int GEr)
{
    int n = blockIdx.x * blockDim.x + threadIdx.x;
    if (n >= n_nodes) return;
    float acc = 0.0f;
#pragma unroll 4
    for (int c = 0; c < GEr; ++c)
        acc += __half2float(partial[(size_t)c * n_nodes + n]);
    row_sum[n] = acc;
}

__global__ __launch_bounds__(256) void edge_norm_kernel(
    const unsigned* __restrict__ packed, const float* __restrict__ row_sum,
    float* __restrict__ out, int n_edges)
{
    int t = blockIdx.x * blockDim.x + threadIdx.x;
    int e0 = t * 8;
    const float inv = 1.0f / 32767.0f;
    if (e0 + 7 < n_edges) {
        v4u pa = ((const v4u*)packed)[t * 2];
        v4u pb = ((const v4u*)packed)[t * 2 + 1];
        float r0 = row_sum[pa.x >> 15];
        float r1 = row_sum[pa.y >> 15];
        float r2 = row_sum[pa.z >> 15];
        float r3 = row_sum[pa.w >> 15];
        float r4 = row_sum[pb.x >> 15];
        float r5 = row_sum[pb.y >> 15];
        float r6 = row_sum[pb.z >> 15];
        float r7 = row_sum[pb.w >> 15];
        v4f oa, ob;
        oa.x = (float)(pa.x & 32767u) * inv / (r0 + EPS);
        oa.y = (float)(pa.y & 32767u) * inv / (r1 + EPS);
        oa.z = (float)(pa.z & 32767u) * inv / (r2 + EPS);
        oa.w = (float)(pa.w & 32767u) * inv / (r3 + EPS);
        ob.x = (float)(pb.x & 32767u) * inv / (r4 + EPS);
        ob.y = (float)(pb.y & 32767u) * inv / (r5 + EPS);
        ob.z = (float)(pb.z & 32767u) * inv / (r6 + EPS);
        ob.w = (float)(pb.w & 32767u) * inv / (r7 + EPS);
        __builtin_nontemporal_store(oa, (v4f*)out + t * 2);
        __builtin_nontemporal_store(ob, (v4f*)out + t * 2 + 1);
    } else if (e0 < n_edges) {
        for (int e = e0; e < n_edges; ++e) {
            unsigned pk = packed[e];
            out[e] = (float)(pk & 32767u) * inv / (row_sum[pk >> 15] + EPS);
        }
    }
}

extern "C" void kernel_launch(void* const* d_in, const int* in_sizes, int n_in,
                              void* d_out, int out_size, void* d_ws, size_t ws_size,
                              hipStream_t stream) {
    const int*    src  = (const int*)d_in[0];
    const int*    dst  = (const int*)d_in[1];
    const float4* emb1 = (const float4*)d_in[2];
    const float4* emb2 = (const float4*)d_in[3];
    float* out = (float*)d_out;

    int n_edges = in_sizes[0];
    int n_emb   = in_sizes[2];          // N_NODES * 16 floats
    int n_nodes = n_emb / 16;

    // ws layout (16B-aligned):
    //   bar     : 512 B (global cnt/gen + 96 chunk counters)
    //   row_sum : n_nodes f32            (400 KB)
    //   packed  : n_edges u32            (12.8 MB)
    //   q1, q2  : n_emb fp8              (1.6 MB each)
    //   partial : FGE*n_nodes f16        (19.2 MB)
    char* base = (char*)d_ws;
    unsigned* bar = (unsigned*)base;
    size_t off = 512;
    float* row_sum = (float*)(base + off);
    off += ((size_t)n_nodes * sizeof(float) + 15) & ~(size_t)15;
    unsigned* packed = (unsigned*)(base + off);
    off += ((size_t)n_edges * sizeof(unsigned) + 15) & ~(size_t)15;
    unsigned* q1 = (unsigned*)(base + off);
    off += ((size_t)n_emb + 15) & ~(size_t)15;
    unsigned* q2 = (unsigned*)(base + off);
    off += ((size_t)n_emb + 15) & ~(size_t)15;
    __half* partial = (__half*)(base + off);

    // One-time host-side checks: dynamic-LDS cap + co-residency proof.
    static int fused_ok = -1;
    if (fused_ok < 0) {
        int dev = 0;
        hipGetDevice(&dev);
        hipError_t e = hipFuncSetAttribute(
            reinterpret_cast<const void*>(&fused_kernel),
            hipFuncAttributeMaxDynamicSharedMemorySize, FPART * 4);
        int nb = 0;
        if (e == hipSuccess)
            e = hipOccupancyMaxActiveBlocksPerMultiprocessor(
                &nb, reinterpret_cast<const void*>(&fused_kernel),
                FBLK, (size_t)FPART * 4);
        int ncu = 0;
        hipDeviceGetAttribute(&ncu, hipDeviceAttributeMultiprocessorCount, dev);
        fused_ok = (e == hipSuccess && nb >= 1 &&
                    (long)nb * ncu >= FGRID) ? 1 : 0;
    }

    if (fused_ok && n_nodes <= FNP * FPART) {
        hipMemsetAsync(bar, 0, 512, stream);   // ws is poisoned between runs
        fused_kernel<<<FGRID, FBLK, (size_t)FPART * 4, stream>>>(
            src, dst, emb1, emb2, q1, q2, packed, partial,
            row_sum, out, bar, n_edges, n_nodes);
        return;
    }

    // ---- fallback: verified split pipeline ----
    static int use_big = -1;
    if (use_big < 0) {
        hipError_t e = hipFuncSetAttribute(
            reinterpret_cast<const void*>(&hist_kernel),
            hipFuncAttributeMaxDynamicSharedMemorySize, 25000 * 4);
        use_big = (e == hipSuccess) ? 1 : 0;
    }
    int PARTr = use_big ? 25000 : 16000;
    int NPr   = use_big ? 4     : 7;
    int GEr   = use_big ? 64    : 37;
    size_t lds_bytes = (size_t)PARTr * sizeof(unsigned);

    int block = 256;
    int n4 = n_emb / 4;
    convert_fp8_kernel<<<(n4 + block - 1) / block, block, 0, stream>>>(
        emb1, emb2, q1, q2, n4);

    int nq = n_edges >> 2;
    int gblocks = (nq + block - 1) / block;
    if (gblocks < 1) gblocks = 1;
    gather_pack_kernel<<<gblocks, block, 0, stream>>>(
        src, dst, (const uint4*)q1, (const uint4*)q2, packed, n_edges);

    hist_kernel<<<GEr * NPr, HBLK, lds_bytes, stream>>>(
        packed, partial, n_edges, n_nodes, PARTr, NPr, GEr);

    fold_kernel<<<(n_nodes + block - 1) / block, block, 0, stream>>>(
        partial, row_sum, n_nodes, GEr);

    int n_oct = (n_edges + 7) / 8;
    edge_norm_kernel<<<(n_oct + block - 1) / block, block, 0, stream>>>(
        packed, row_sum, out, n_edges);
}